// Round 10
// baseline (84.988 us; speedup 1.0000x reference)
//
#include <hip/hip_runtime.h>
#include <hip/hip_bf16.h>
#include <stdint.h>

#define NPTS 4096
#define NNBR 16      // neighbors kept (reference keeps 17 incl. self, drops self)
#define PPB  16      // points per block
#define NSEG 32      // candidate segments (one per t>>4 group)
#define SEGLEN 128   // candidates per segment
#define SEGPAD 132   // 132 % 32 == 4: the 4 segs in a wave land on bank-quads 0/4/8/12
#define HSTR 65      // heads/plist stride in floats
#define LSTR 145     // list stride (uints)
#define CAP  144     // accepted-candidate capacity (rank(tau) ~ 34-70, tail-safe)
#define TAUM 1.0e-3f // proxy-vs-pinned margin (bound ~1e-4; 10x safety)
#define BIGD 3.4e38f

// ---------------------------------------------------------------------------
// PINNED distance (numpy-order, no contraction) — used ONLY in the final
// threshold/marking phases so the selected neighbor set is bitwise-stable:
//   d2 = (sqp + sqq) - (dot + dot),  sqq = (x*x + y*y) + z*z
// Recomputed from staged f32 coords -> bit-identical across phases & rounds.
// ---------------------------------------------------------------------------
__device__ __forceinline__ float sqnorm(float x, float y, float z) {
    return __fadd_rn(__fadd_rn(__fmul_rn(x, x), __fmul_rn(y, y)), __fmul_rn(z, z));
}
__device__ __forceinline__ float d2w(float px, float py, float pz, float sqp,
                                     float cx, float cy, float cz) {
    const float sqq = sqnorm(cx, cy, cz);
    const float dot = __fadd_rn(__fadd_rn(__fmul_rn(px, cx), __fmul_rn(py, cy)),
                                __fmul_rn(pz, cz));
    return __fsub_rn(__fadd_rn(sqp, sqq), __fadd_rn(dot, dot));
}
// CHEAP monotone proxy for the scans (7 VALU, sqq recomputed in-register).
// ONE inline function used by BOTH pre-pass and scan2 -> identical bits for
// the same candidate; TAUM covers proxy-vs-pinned cross-space rounding.
__device__ __forceinline__ float eproxy2(float px, float py, float pz,
                                         float cx, float cy, float cz) {
    const float sqq = __builtin_fmaf(cz, cz, __builtin_fmaf(cy, cy, __fmul_rn(cx, cx)));
    const float dot = __builtin_fmaf(px, cx, __builtin_fmaf(py, cy, __fmul_rn(pz, cz)));
    return __builtin_fmaf(dot, -2.0f, sqq);
}

// generic K-deep min/max ladder over a register array (static unroll only)
#define LADK(AD, K, S)                                            \
    _Pragma("unroll")                                             \
    for (int k_ = 0; k_ < (K); ++k_) {                            \
        const float lo_ = fminf((S), AD[k_]);                     \
        (S) = fmaxf((S), AD[k_]);                                 \
        AD[k_] = lo_;                                             \
    }

// two smallest of a quad + merge into sorted pair (A0<=A1): 12 VALU
#define TOP2MERGE(S0, S1, S2, S3, A0, A1) {                       \
    const float m01_ = fminf(S0, S1), M01_ = fmaxf(S0, S1);       \
    const float m23_ = fminf(S2, S3), M23_ = fmaxf(S2, S3);       \
    const float mm_  = fminf(m01_, m23_);                         \
    const float ss_  = fminf(fmaxf(m01_, m23_), fminf(M01_, M23_));\
    const float n0_  = fminf(A0, mm_);                            \
    A1 = fminf(fmaxf(A0, mm_), fminf(A1, ss_));                   \
    A0 = n0_; }

// ---------------------------------------------------------------------------
// Fused exact 16-NN. Block = 512 thr = 16 points x 32 segments, grid = 1024.
// Round-9 skeleton with the LDS-traffic diet:
//  - no sw array: sqq recomputed in-register (scans 3 b128/quad instead of 4)
//  - pre-pass: per-seg top-2 proxy over EVEN quads only (1/2 subsample, 64
//    cands/thread). Any >=17-element subset's 17th order-stat >= full-set
//    d2_(17)  =>  tau remains a valid (looser) bound; CAP raised to 144.
//  - scan2 + pinned-d2 final phases unchanged (identical neighbor sets).
// ---------------------------------------------------------------------------
__global__ __launch_bounds__(512, 4) void knn_kernel(const float* __restrict__ x0,
                                                     ushort* __restrict__ nbr) {
    __shared__ float sx[NSEG * SEGPAD], sy[NSEG * SEGPAD],
                     sz[NSEG * SEGPAD];                          // 3 x 16,896 B
    __shared__ float mbuf[PPB * HSTR];                           // heads; later plist
    __shared__ uint  list[PPB * LSTR];                           // accepted indices
    __shared__ float ttau[PPB][2];
    __shared__ float t16[PPB];
    __shared__ int   cnt[PPB], cnt2[PPB];

    const int b     = blockIdx.x >> 8;       // 256 chunks per batch
    const int chunk = blockIdx.x & 255;
    const float* Xb = x0 + b * (NPTS * 3);
    const int t = threadIdx.x;

    for (int i = t; i < NPTS; i += 512) {
        const int a = (i >> 7) * SEGPAD + (i & 127);
        sx[a] = Xb[3 * i + 0];
        sy[a] = Xb[3 * i + 1];
        sz[a] = Xb[3 * i + 2];
    }
    if (t < PPB) { cnt[t] = 0; cnt2[t] = 0; }
    __syncthreads();

    const int pt = t & 15, seg = t >> 4;     // seg 0..31
    const int p  = chunk * PPB + pt;         // batch-local point id
    const int pa = (p >> 7) * SEGPAD + (p & 127);
    const float px = sx[pa], py = sy[pa], pz = sz[pa];
    const int sb = seg * SEGPAD;

    // ---- pre-pass: per-seg top-2 proxy over EVEN quads (64 cands) ----
    float a0 = BIGD, a1 = BIGD;
    for (int j = 0; j < 32; j += 2) {
        const int o = sb + 4 * j;
        const float4 cx4 = *(const float4*)&sx[o];
        const float4 cy4 = *(const float4*)&sy[o];
        const float4 cz4 = *(const float4*)&sz[o];
        const float s0 = eproxy2(px, py, pz, cx4.x, cy4.x, cz4.x);
        const float s1 = eproxy2(px, py, pz, cx4.y, cy4.y, cz4.y);
        const float s2 = eproxy2(px, py, pz, cx4.z, cy4.z, cz4.z);
        const float s3 = eproxy2(px, py, pz, cx4.w, cy4.w, cz4.w);
        TOP2MERGE(s0, s1, s2, s3, a0, a1)
    }
    mbuf[pt * HSTR + seg * 2 + 0] = a0;
    mbuf[pt * HSTR + seg * 2 + 1] = a1;
    __syncthreads();

    // ---- tau: 2 thr/pt, LAD17 over one 32-value half (rotated reads) ----
    if (t < 32) {
        const int pm = t >> 1, half = t & 1;
        float ad[17];
#pragma unroll
        for (int k = 0; k < 17; ++k) ad[k] = BIGD;
        const int base = pm * HSTR + half * 32;
        for (int e = 0; e < 32; ++e) {
            float s = mbuf[base + ((e + 2 * t) & 31)];
            LADK(ad, 17, s)
        }
        ttau[pm][half] = ad[16];             // this half's 17th-smallest
    }
    __syncthreads();

    // ---- scan2: branchless accept-bitmask per 32-cand word + extraction ----
    const float tv = fminf(ttau[pt][0], ttau[pt][1]) + TAUM;
    for (int w = 0; w < 4; ++w) {
        uint m = 0;
#pragma unroll
        for (int jj = 0; jj < 8; ++jj) {
            const int o = sb + w * 32 + 4 * jj;
            const float4 cx4 = *(const float4*)&sx[o];
            const float4 cy4 = *(const float4*)&sy[o];
            const float4 cz4 = *(const float4*)&sz[o];
            const float s0 = eproxy2(px, py, pz, cx4.x, cy4.x, cz4.x);
            const float s1 = eproxy2(px, py, pz, cx4.y, cy4.y, cz4.y);
            const float s2 = eproxy2(px, py, pz, cx4.z, cy4.z, cz4.z);
            const float s3 = eproxy2(px, py, pz, cx4.w, cy4.w, cz4.w);
            m |= (s0 <= tv) ? (1u << (4 * jj + 0)) : 0u;
            m |= (s1 <= tv) ? (1u << (4 * jj + 1)) : 0u;
            m |= (s2 <= tv) ? (1u << (4 * jj + 2)) : 0u;
            m |= (s3 <= tv) ? (1u << (4 * jj + 3)) : 0u;
        }
        while (m) {                          // ~1-2 set bits/thread total
            const int bpos = __ffs(m) - 1;
            m &= m - 1;
            const int q = seg * SEGLEN + w * 32 + bpos;   // batch-local cand id
            if (q != p) {
                const int o = atomicAdd(&cnt[pt], 1);
                if (o < CAP) list[pt * LSTR + o] = (uint)q;
            }
        }
    }
    __syncthreads();

    // ---- final 3a: 4 thr/pt, PINNED-d2 LAD16 over stride-4 slice ----
    if (t < 64) {
        const int p2 = t >> 2, sl = t & 3;
        const int n  = min(cnt[p2], CAP);
        const int pg  = chunk * PPB + p2;
        const int pa2 = (pg >> 7) * SEGPAD + (pg & 127);
        const float ax = sx[pa2], ay = sy[pa2], az = sz[pa2];
        const float sqa = sqnorm(ax, ay, az);
        float ad[16];
#pragma unroll
        for (int k = 0; k < 16; ++k) ad[k] = BIGD;
        for (int e = sl; e < n; e += 4) {
            const int q  = (int)list[p2 * LSTR + e];
            const int qa = (q >> 7) * SEGPAD + (q & 127);
            float s = d2w(ax, ay, az, sqa, sx[qa], sy[qa], sz[qa]);
            LADK(ad, 16, s)
        }
#pragma unroll
        for (int k = 0; k < 16; ++k) mbuf[p2 * HSTR + sl * 16 + k] = ad[k];
    }
    __syncthreads();

    // ---- final 3b: 1 thr/pt, exact 16th-smallest pinned d2 among accepted ----
    if (t < PPB) {
        float ad[16];
#pragma unroll
        for (int k = 0; k < 16; ++k) ad[k] = BIGD;
        for (int e = 0; e < 64; ++e) {
            float s = mbuf[t * HSTR + ((e + t) & 63)];
            LADK(ad, 16, s)
        }
        t16[t] = ad[15];
    }
    __syncthreads();

    // ---- final 3c: marking pass emits the 16 indices with pinned d2 <= th ----
    if (t < 64) {
        const int p2 = t >> 2, sl = t & 3;
        const int n  = min(cnt[p2], CAP);
        const int pg  = chunk * PPB + p2;
        const int pa2 = (pg >> 7) * SEGPAD + (pg & 127);
        const float ax = sx[pa2], ay = sy[pa2], az = sz[pa2];
        const float sqa = sqnorm(ax, ay, az);
        const float th = t16[p2];
        const uint base = (uint)(b * NPTS + pg) * (uint)NNBR;
        for (int e = sl; e < n; e += 4) {
            const int q  = (int)list[p2 * LSTR + e];
            const int qa = (q >> 7) * SEGPAD + (q & 127);
            const float s = d2w(ax, ay, az, sqa, sx[qa], sy[qa], sz[qa]);
            if (s <= th) {
                const int o = atomicAdd(&cnt2[p2], 1);
                if (o < NNBR) nbr[base + o] = (ushort)q;
            }
        }
    }
}

// ---------------------------------------------------------------------------
// MLP + neighbor mean (one wave per point, lane = output channel) with the
// v0 passthrough copy folded in (first 48 blocks copy one float4/thread).
// ---------------------------------------------------------------------------
__global__ __launch_bounds__(256) void mlp_kernel(const float* __restrict__ x0,
                                                  const float* __restrict__ v0,
                                                  const float* __restrict__ W,
                                                  const float* __restrict__ bias,
                                                  const ushort* __restrict__ nbr,
                                                  float* __restrict__ out) {
    const int t   = threadIdx.x;
    const int gid = blockIdx.x * 256 + t;
    if (gid < (4 * NPTS * 3) / 4) {                 // 12288 float4 copies
        ((float4*)(out + 4 * NPTS * 64))[gid] = ((const float4*)v0)[gid];
    }

    const int wave = t >> 6;
    const int lane = t & 63;
    const int gp   = blockIdx.x * 4 + wave;         // global point id 0..16383
    const int b    = gp >> 12;
    const int p    = gp & (NPTS - 1);

    const float* Xb = x0 + b * (NPTS * 3);
    const float* Vb = v0 + b * (NPTS * 3);

    float w[12];
#pragma unroll
    for (int k = 0; k < 12; ++k) w[k] = W[k * 64 + lane];
    const float bb = bias[lane];

    const float xi0 = Xb[p * 3 + 0], xi1 = Xb[p * 3 + 1], xi2 = Xb[p * 3 + 2];
    const float vi0 = Vb[p * 3 + 0], vi1 = Vb[p * 3 + 1], vi2 = Vb[p * 3 + 2];

    const float base = bb + w[0] * xi0 + w[1] * xi1 + w[2] * xi2
                          + w[6] * vi0 + w[7] * vi1 + w[8] * vi2;

    __shared__ float nb[4][NNBR][8];
    if (lane < NNBR) {
        const int j = (int)nbr[(uint)gp * NNBR + lane];
        nb[wave][lane][0] = Xb[j * 3 + 0];
        nb[wave][lane][1] = Xb[j * 3 + 1];
        nb[wave][lane][2] = Xb[j * 3 + 2];
        nb[wave][lane][3] = Vb[j * 3 + 0];
        nb[wave][lane][4] = Vb[j * 3 + 1];
        nb[wave][lane][5] = Vb[j * 3 + 2];
    }
    __syncthreads();

    float acc = 0.0f;
#pragma unroll
    for (int n = 0; n < NNBR; ++n) {
        const float h = base + w[3]  * nb[wave][n][0] + w[4]  * nb[wave][n][1]
                             + w[5]  * nb[wave][n][2] + w[9]  * nb[wave][n][3]
                             + w[10] * nb[wave][n][4] + w[11] * nb[wave][n][5];
        acc += fmaxf(h, 0.0f);
    }

    out[(size_t)gp * 64 + lane] = acc * (1.0f / 16.0f);
}

extern "C" void kernel_launch(void* const* d_in, const int* in_sizes, int n_in,
                              void* d_out, int out_size, void* d_ws, size_t ws_size,
                              hipStream_t stream) {
    const float* x0 = (const float*)d_in[0];   // (4, 12288)
    const float* v0 = (const float*)d_in[1];   // (4, 12288)
    const float* W  = (const float*)d_in[2];   // (12, 64)
    const float* bb = (const float*)d_in[3];   // (64,)
    float* out = (float*)d_out;

    ushort* nbr = (ushort*)d_ws;               // 16384 * 16 * 2B = 512 KB

    // 1) fused exact 16-NN: 1024 blocks (4 batches x 256 chunks of 16 points),
    //    512 threads (16 pts x 32 segs).
    knn_kernel<<<1024, 512, 0, stream>>>(x0, nbr);

    // 2) MLP + mean (+ folded v0 copy): 4 points/block, 4096 blocks.
    mlp_kernel<<<4096, 256, 0, stream>>>(x0, v0, W, bb, nbr, out);
}

// Round 11
// 68.715 us; speedup vs baseline: 1.2368x; 1.2368x over previous
//
#include <hip/hip_runtime.h>
#include <hip/hip_bf16.h>
#include <stdint.h>

#define NPTS 4096
#define NNBR 16      // neighbors kept (reference keeps 17 incl. self, drops self)
#define PPB  16      // points per block
#define NSEG 32      // candidate segments (one per t>>4 group)
#define SEGLEN 128   // candidates per segment
#define SEGPAD 132   // 132 % 32 == 4: the 4 segs in a wave land on bank-quads 0/4/8/12
#define HSTR 65      // heads stride in floats
#define CAP  96      // accepted-candidate capacity (rank(tau) ~ 20-40)
#define TAUM 1.0e-3f // proxy-vs-pinned margin (bound ~4e-5; 25x safety)
#define BIGD 3.4e38f

// ---------------------------------------------------------------------------
// PINNED distance (numpy-order, no contraction) — used for the accepted-list
// d2 values so the selected neighbor set is bitwise-stable:
//   d2 = (sqp + sqq) - (dot + dot), sqq staged in sw with pinned sqnorm bits.
// ---------------------------------------------------------------------------
__device__ __forceinline__ float sqnorm(float x, float y, float z) {
    return __fadd_rn(__fadd_rn(__fmul_rn(x, x), __fmul_rn(y, y)), __fmul_rn(z, z));
}
__device__ __forceinline__ float d2w(float px, float py, float pz, float sqp,
                                     float cx, float cy, float cz, float sqq) {
    const float dot = __fadd_rn(__fadd_rn(__fmul_rn(px, cx), __fmul_rn(py, cy)),
                                __fmul_rn(pz, cz));
    return __fsub_rn(__fadd_rn(sqp, sqq), __fadd_rn(dot, dot));
}
// CHEAP monotone proxy for the scans: e = sqq - 2*dot (= d2 - sqp up to ~ulps).
// TAUM margin in scan2 absorbs all proxy-vs-pinned rounding differences.
__device__ __forceinline__ float eproxy(float px, float py, float pz,
                                        float cx, float cy, float cz, float sqq) {
    const float dot = __builtin_fmaf(px, cx, __builtin_fmaf(py, cy, __fmul_rn(pz, cz)));
    return __builtin_fmaf(dot, -2.0f, sqq);
}

// generic K-deep min/max ladder over a register array (static unroll only)
#define LADK(AD, K, S)                                            \
    _Pragma("unroll")                                             \
    for (int k_ = 0; k_ < (K); ++k_) {                            \
        const float lo_ = fminf((S), AD[k_]);                     \
        (S) = fmaxf((S), AD[k_]);                                 \
        AD[k_] = lo_;                                             \
    }

// two smallest of a quad + merge into sorted pair (A0<=A1): 12 VALU
#define TOP2MERGE(S0, S1, S2, S3, A0, A1) {                       \
    const float m01_ = fminf(S0, S1), M01_ = fmaxf(S0, S1);       \
    const float m23_ = fminf(S2, S3), M23_ = fmaxf(S2, S3);       \
    const float mm_  = fminf(m01_, m23_);                         \
    const float ss_  = fminf(fmaxf(m01_, m23_), fminf(M01_, M23_));\
    const float n0_  = fminf(A0, mm_);                            \
    A1 = fminf(fmaxf(A0, mm_), fminf(A1, ss_));                   \
    A0 = n0_; }

// ---------------------------------------------------------------------------
// Fused exact 16-NN. Block = 512 thr = 16 points x 32 segments, grid = 1024.
// Scan structure IDENTICAL to round 9 (proven 70us / FETCH ~0.9MB):
//  scan1 : per-seg top-2 of proxy-e, dual independent chains.
//  tau   : 2 thr/pt LAD17 over one 32-value half of heads; tau = min of two.
//  scan2 : branchless {e <= tau+TAUM} bitmask; extraction appends
//          (PINNED d2, idx) float2 to the per-point list (atomic, CAP=96).
// NEW final: rank-by-counting — thread (pt, slot) computes, for each of its
// accepted entries e, rank = #{f : (d2_f, idx_f) < (d2_e, idx_e)}; rank < 16
// writes nbr[base+rank] directly. One phase, all 512 threads active, no
// threshold ladders, no atomics, deterministic output order (ascending d2).
// Exactness: accepted contains the true 16-NN (tau bound unchanged), and the
// strict total order (d2, idx) assigns ranks 0..15 to exactly those 16.
// ---------------------------------------------------------------------------
__global__ __launch_bounds__(512, 4) void knn_kernel(const float* __restrict__ x0,
                                                     ushort* __restrict__ nbr) {
    __shared__ float sx[NSEG * SEGPAD], sy[NSEG * SEGPAD],
                     sz[NSEG * SEGPAD], sw[NSEG * SEGPAD];   // 4 x 16,896 B
    __shared__ float2 list[PPB * CAP];                       // 12,288 B
    __shared__ float ttau[PPB][2];
    __shared__ int   cnt[PPB];

    float* heads = (float*)list;             // alias: heads dead before extraction

    const int b     = blockIdx.x >> 8;       // 256 chunks per batch
    const int chunk = blockIdx.x & 255;
    const float* Xb = x0 + b * (NPTS * 3);
    const int t = threadIdx.x;

    for (int i = t; i < NPTS; i += 512) {
        const int a = (i >> 7) * SEGPAD + (i & 127);
        const float x = Xb[3 * i + 0];
        const float y = Xb[3 * i + 1];
        const float z = Xb[3 * i + 2];
        sx[a] = x; sy[a] = y; sz[a] = z; sw[a] = sqnorm(x, y, z);
    }
    if (t < PPB) cnt[t] = 0;
    __syncthreads();

    const int pt = t & 15, seg = t >> 4;     // seg 0..31
    const int p  = chunk * PPB + pt;         // batch-local point id
    const int pa = (p >> 7) * SEGPAD + (p & 127);
    const float px = sx[pa], py = sy[pa], pz = sz[pa], sqp = sw[pa];
    const int sb = seg * SEGPAD;

    // ---- scan1: per-seg top-2 of proxy-e, dual independent chains ----
    float a0 = BIGD, a1 = BIGD;              // chain A (even quads)
    float b0 = BIGD, b1 = BIGD;              // chain B (odd quads)
    for (int j = 0; j < 32; j += 2) {
        const int oa = sb + 4 * j;
        const int ob = oa + 4;
        const float4 cxa = *(const float4*)&sx[oa];
        const float4 cya = *(const float4*)&sy[oa];
        const float4 cza = *(const float4*)&sz[oa];
        const float4 cwa = *(const float4*)&sw[oa];
        const float4 cxb = *(const float4*)&sx[ob];
        const float4 cyb = *(const float4*)&sy[ob];
        const float4 czb = *(const float4*)&sz[ob];
        const float4 cwb = *(const float4*)&sw[ob];
        const float sa0 = eproxy(px, py, pz, cxa.x, cya.x, cza.x, cwa.x);
        const float sa1 = eproxy(px, py, pz, cxa.y, cya.y, cza.y, cwa.y);
        const float sa2 = eproxy(px, py, pz, cxa.z, cya.z, cza.z, cwa.z);
        const float sa3 = eproxy(px, py, pz, cxa.w, cya.w, cza.w, cwa.w);
        const float sb0 = eproxy(px, py, pz, cxb.x, cyb.x, czb.x, cwb.x);
        const float sb1 = eproxy(px, py, pz, cxb.y, cyb.y, czb.y, cwb.y);
        const float sb2 = eproxy(px, py, pz, cxb.z, cyb.z, czb.z, cwb.z);
        const float sb3 = eproxy(px, py, pz, cxb.w, cyb.w, czb.w, cwb.w);
        TOP2MERGE(sa0, sa1, sa2, sa3, a0, a1)
        TOP2MERGE(sb0, sb1, sb2, sb3, b0, b1)
    }
    {   // exact merge of the two sorted pairs -> segment top-2
        const float n0 = fminf(a0, b0);
        a1 = fminf(fmaxf(a0, b0), fminf(a1, b1));
        a0 = n0;
    }
    heads[pt * HSTR + seg * 2 + 0] = a0;
    heads[pt * HSTR + seg * 2 + 1] = a1;
    __syncthreads();

    // ---- tau: 2 thr/pt, LAD17 over one 32-value half (rotated reads) ----
    if (t < 32) {
        const int pm = t >> 1, half = t & 1;
        float ad[17];
#pragma unroll
        for (int k = 0; k < 17; ++k) ad[k] = BIGD;
        const int base = pm * HSTR + half * 32;
        for (int e = 0; e < 32; ++e) {
            float s = heads[base + ((e + 2 * t) & 31)];
            LADK(ad, 17, s)
        }
        ttau[pm][half] = ad[16];             // this half's 17th-smallest
    }
    __syncthreads();                         // heads dead; list reuses the space

    // ---- scan2: branchless accept-bitmask per 32-cand word + extraction ----
    const float tv = fminf(ttau[pt][0], ttau[pt][1]) + TAUM;
    for (int w = 0; w < 4; ++w) {
        uint m = 0;
#pragma unroll
        for (int jj = 0; jj < 8; ++jj) {
            const int o = sb + w * 32 + 4 * jj;
            const float4 cx4 = *(const float4*)&sx[o];
            const float4 cy4 = *(const float4*)&sy[o];
            const float4 cz4 = *(const float4*)&sz[o];
            const float4 cw4 = *(const float4*)&sw[o];
            const float s0 = eproxy(px, py, pz, cx4.x, cy4.x, cz4.x, cw4.x);
            const float s1 = eproxy(px, py, pz, cx4.y, cy4.y, cz4.y, cw4.y);
            const float s2 = eproxy(px, py, pz, cx4.z, cy4.z, cz4.z, cw4.z);
            const float s3 = eproxy(px, py, pz, cx4.w, cy4.w, cz4.w, cw4.w);
            m |= (s0 <= tv) ? (1u << (4 * jj + 0)) : 0u;
            m |= (s1 <= tv) ? (1u << (4 * jj + 1)) : 0u;
            m |= (s2 <= tv) ? (1u << (4 * jj + 2)) : 0u;
            m |= (s3 <= tv) ? (1u << (4 * jj + 3)) : 0u;
        }
        while (m) {                          // ~1 set bit/thread total
            const int bpos = __ffs(m) - 1;
            m &= m - 1;
            const int q = seg * SEGLEN + w * 32 + bpos;   // batch-local cand id
            if (q != p) {
                const int qa = (q >> 7) * SEGPAD + (q & 127);
                const float d2 = d2w(px, py, pz, sqp,
                                     sx[qa], sy[qa], sz[qa], sw[qa]);  // PINNED
                const int o = atomicAdd(&cnt[pt], 1);
                if (o < CAP) list[pt * CAP + o] = make_float2(d2, __int_as_float(q));
            }
        }
    }
    __syncthreads();

    // ---- final: rank-by-counting, all 512 threads (32 slots x 16 points) ----
    {
        const int p2 = t >> 5;               // point 0..15
        const int sl = t & 31;               // slot 0..31
        const int n  = min(cnt[p2], CAP);
        const uint base = (uint)(b * NPTS + chunk * PPB + p2) * (uint)NNBR;
        for (int e = sl; e < n; e += 32) {
            const float2 ve = list[p2 * CAP + e];
            const int ie = __float_as_int(ve.y);
            int r = 0;
            for (int f = 0; f < n; ++f) {
                const float2 vf = list[p2 * CAP + f];
                const bool lt = (vf.x < ve.x) ||
                                (vf.x == ve.x && __float_as_int(vf.y) < ie);
                r += lt ? 1 : 0;
            }
            if (r < NNBR) nbr[base + r] = (ushort)ie;
        }
    }
}

// ---------------------------------------------------------------------------
// MLP + neighbor mean (one wave per point, lane = output channel) with the
// v0 passthrough copy folded in (first 48 blocks copy one float4/thread).
// ---------------------------------------------------------------------------
__global__ __launch_bounds__(256) void mlp_kernel(const float* __restrict__ x0,
                                                  const float* __restrict__ v0,
                                                  const float* __restrict__ W,
                                                  const float* __restrict__ bias,
                                                  const ushort* __restrict__ nbr,
                                                  float* __restrict__ out) {
    const int t   = threadIdx.x;
    const int gid = blockIdx.x * 256 + t;
    if (gid < (4 * NPTS * 3) / 4) {                 // 12288 float4 copies
        ((float4*)(out + 4 * NPTS * 64))[gid] = ((const float4*)v0)[gid];
    }

    const int wave = t >> 6;
    const int lane = t & 63;
    const int gp   = blockIdx.x * 4 + wave;         // global point id 0..16383
    const int b    = gp >> 12;
    const int p    = gp & (NPTS - 1);

    const float* Xb = x0 + b * (NPTS * 3);
    const float* Vb = v0 + b * (NPTS * 3);

    float w[12];
#pragma unroll
    for (int k = 0; k < 12; ++k) w[k] = W[k * 64 + lane];
    const float bb = bias[lane];

    const float xi0 = Xb[p * 3 + 0], xi1 = Xb[p * 3 + 1], xi2 = Xb[p * 3 + 2];
    const float vi0 = Vb[p * 3 + 0], vi1 = Vb[p * 3 + 1], vi2 = Vb[p * 3 + 2];

    const float base = bb + w[0] * xi0 + w[1] * xi1 + w[2] * xi2
                          + w[6] * vi0 + w[7] * vi1 + w[8] * vi2;

    __shared__ float nb[4][NNBR][8];
    if (lane < NNBR) {
        const int j = (int)nbr[(uint)gp * NNBR + lane];
        nb[wave][lane][0] = Xb[j * 3 + 0];
        nb[wave][lane][1] = Xb[j * 3 + 1];
        nb[wave][lane][2] = Xb[j * 3 + 2];
        nb[wave][lane][3] = Vb[j * 3 + 0];
        nb[wave][lane][4] = Vb[j * 3 + 1];
        nb[wave][lane][5] = Vb[j * 3 + 2];
    }
    __syncthreads();

    float acc = 0.0f;
#pragma unroll
    for (int n = 0; n < NNBR; ++n) {
        const float h = base + w[3]  * nb[wave][n][0] + w[4]  * nb[wave][n][1]
                             + w[5]  * nb[wave][n][2] + w[9]  * nb[wave][n][3]
                             + w[10] * nb[wave][n][4] + w[11] * nb[wave][n][5];
        acc += fmaxf(h, 0.0f);
    }

    out[(size_t)gp * 64 + lane] = acc * (1.0f / 16.0f);
}

extern "C" void kernel_launch(void* const* d_in, const int* in_sizes, int n_in,
                              void* d_out, int out_size, void* d_ws, size_t ws_size,
                              hipStream_t stream) {
    const float* x0 = (const float*)d_in[0];   // (4, 12288)
    const float* v0 = (const float*)d_in[1];   // (4, 12288)
    const float* W  = (const float*)d_in[2];   // (12, 64)
    const float* bb = (const float*)d_in[3];   // (64,)
    float* out = (float*)d_out;

    ushort* nbr = (ushort*)d_ws;               // 16384 * 16 * 2B = 512 KB

    // 1) fused exact 16-NN: 1024 blocks (4 batches x 256 chunks of 16 points),
    //    512 threads (16 pts x 32 segs).
    knn_kernel<<<1024, 512, 0, stream>>>(x0, nbr);

    // 2) MLP + mean (+ folded v0 copy): 4 points/block, 4096 blocks.
    mlp_kernel<<<4096, 256, 0, stream>>>(x0, v0, W, bb, nbr, out);
}